// Round 7
// baseline (105.306 us; speedup 1.0000x reference)
//
#include <hip/hip_runtime.h>
#include <hip/hip_bf16.h>
#include <stdint.h>

typedef __attribute__((ext_vector_type(8))) __bf16 bf16x8;
typedef __attribute__((ext_vector_type(4))) float  f32x4;
typedef unsigned short ushort_t;

#define MFMA16(a, b, c) __builtin_amdgcn_mfma_f32_16x16x32_bf16((a), (b), (c), 0, 0, 0)

__device__ __forceinline__ ushort_t f2b(float f) {
    union { float f; uint32_t u; } v; v.f = f;
    uint32_t r = v.u + 0x7FFFu + ((v.u >> 16) & 1u);
    return (ushort_t)(r >> 16);
}
__device__ __forceinline__ float b2f(ushort_t u) {
    union { uint32_t u; float f; } v; v.u = (uint32_t)u << 16;
    return v.f;
}

#define GLDS16(g, l)                                                          \
    __builtin_amdgcn_global_load_lds(                                         \
        (const __attribute__((address_space(1))) void*)(g),                   \
        (__attribute__((address_space(3))) void*)(l), 16, 0, 0)

// per-phase counted vmcnt: steady 6 (3 half-stages in flight); tail 6->2->0
#define VMW(t, s)                                                             \
    if ((t) < NKT - 2)      { asm volatile("s_waitcnt vmcnt(6)" ::: "memory"); } \
    else if ((t) == NKT - 2) {                                                \
        if ((s) < 3)        { asm volatile("s_waitcnt vmcnt(6)" ::: "memory"); } \
        else                { asm volatile("s_waitcnt vmcnt(2)" ::: "memory"); } \
    } else {                                                                  \
        if ((s) == 0)       { asm volatile("s_waitcnt vmcnt(0)" ::: "memory"); } \
    }

// ---------------------------------------------------------------------------
// fused fp32 -> bf16 convert for X, B, C in one launch (x4 vectorized)
// ---------------------------------------------------------------------------
__global__ __launch_bounds__(256) void cvt3(const float* __restrict__ X, ushort_t* __restrict__ Xb,
                                            const float* __restrict__ B, ushort_t* __restrict__ Bb,
                                            const float* __restrict__ C, ushort_t* __restrict__ Cb) {
    const int b = blockIdx.x;
    const float* src; ushort_t* dst; int base;
    if (b < 16384)      { src = X; dst = Xb; base = b; }
    else if (b < 17408) { src = B; dst = Bb; base = b - 16384; }
    else                { src = C; dst = Cb; base = b - 17408; }
    const int idx = (base * 256 + threadIdx.x) * 4;
    float4 v = *(const float4*)&src[idx];
    ushort4 o;
    o.x = f2b(v.x); o.y = f2b(v.y); o.z = f2b(v.z); o.w = f2b(v.w);
    *(ushort4*)&dst[idx] = o;
}

// ---------------------------------------------------------------------------
// 256x256 bf16 GEMM, T3+T4 pipeline: 4 phases/K-tile, K-half staging (16KB
// halves), 2 tile-buffers, per-phase counted vmcnt(6), 1 barrier/phase,
// setprio around each 16-MFMA cluster. Slot-reuse proof: each half's slot is
// freed (last read) exactly 1 phase before its re-stage; every read targets
// a half staged >=5 phases earlier; vmcnt(6) leaves only the newest 3
// half-stages outstanding.
// LDS: buf[2] x { A[kh0 16K][kh1 16K] | B[kh0][kh1] } = 128 KB dynamic.
// Layout per half: [row 0..255][32 k = 64B], chunk-swizzle ch^((row>>1)&3)
// -> 2 lanes/bank on ds_read_b128 (free).
// gemm1_scan additionally computes a 16-row warmup strip (rows row0-16..-1)
// and solves h_t = nu*h_{t-1} + Bu_t in the epilogue (window 16; |nu|<=1/32).
// ---------------------------------------------------------------------------
__global__ __launch_bounds__(512, 2) void gemm1_scan(const ushort_t* __restrict__ A,
                                                     const ushort_t* __restrict__ W,
                                                     ushort_t* __restrict__ Hb,
                                                     int M, int N, int K,
                                                     const float* __restrict__ nu_log) {
    extern __shared__ char smem[];
    __shared__ ushort_t wstrip[16 * 256];        // warmup Bu strip (bf16)
    __shared__ ushort_t wabuf[2][2][512];        // warmup A: [tile&1][kh][1KB]

    const int tid  = threadIdx.x;
    const int lane = tid & 63;
    const int w    = tid >> 6;
    const int wm   = w >> 2;
    const int wn   = w & 3;

    const int nwg = gridDim.x;
    const int cpx = nwg >> 3;
    const int bid = (blockIdx.x & 7) * cpx + (blockIdx.x >> 3);
    const int nbn = N >> 8;
    const int row0 = (bid / nbn) << 8;
    const int col0 = (bid % nbn) << 8;
    const int NKT = K >> 6;

    // staging: chunk q = j*512+tid -> row = j*128 + (tid>>2), col-chunk tid&3
    // holds swizzled global chunk (tid&3)^((tid>>3)&3)
    const int g8e = (((tid & 3) ^ ((tid >> 3) & 3)) << 3);
    const ushort_t* asrc0 = A + (size_t)(row0 +       (tid >> 2)) * K + g8e;
    const ushort_t* asrc1 = A + (size_t)(row0 + 128 + (tid >> 2)) * K + g8e;
    const ushort_t* bsrc0 = W + (size_t)(col0 +       (tid >> 2)) * K + g8e;
    const ushort_t* bsrc1 = W + (size_t)(col0 + 128 + (tid >> 2)) * K + g8e;
    const ushort_t* wsrc  = A + (size_t)(row0 - 16 + (tid >> 2)) * K + g8e; // wave0 only

#define STG_A(buf, kh, kt) do {                                               \
    char* _d = smem + (buf) * 65536 + (kh) * 16384 + tid * 16;                \
    const size_t _o = (size_t)(kt) * 64 + (kh) * 32;                          \
    GLDS16(asrc0 + _o, _d);                                                   \
    GLDS16(asrc1 + _o, _d + 8192); } while (0)
#define STG_B(buf, kh, kt) do {                                               \
    char* _d = smem + (buf) * 65536 + 32768 + (kh) * 16384 + tid * 16;        \
    const size_t _o = (size_t)(kt) * 64 + (kh) * 32;                          \
    GLDS16(bsrc0 + _o, _d);                                                   \
    GLDS16(bsrc1 + _o, _d + 8192); } while (0)
#define STG_W(par, kh, kt) do { if (row0 && w == 0) {                         \
    GLDS16(wsrc + (size_t)(kt) * 64 + (kh) * 32,                              \
           (char*)&wabuf[par][kh][0] + tid * 16); } } while (0)

    // fragment lane offset within a 16KB half (row l15-ish, swizzled chunk)
    const int lb = (lane & 15) * 64 + ((((lane >> 4) ^ ((lane >> 1) & 3))) << 4);
    const bool do_w = (wm == 0) && row0;

    f32x4 acc[8][4] = {};
    f32x4 acc_w[4] = {};

    // prologue: tile0 (all 4 halves) + tile1 kh0 halves (+warmups)
    STG_A(0, 0, 0); STG_B(0, 0, 0);
    STG_A(0, 1, 0); STG_B(0, 1, 0);
    STG_A(1, 0, 1); STG_B(1, 0, 1);
    STG_W(0, 0, 0); STG_W(0, 1, 0); STG_W(1, 0, 1);
    asm volatile("s_waitcnt vmcnt(0)" ::: "memory");
    __builtin_amdgcn_s_barrier();

    for (int t = 0; t < NKT; ++t) {
        const int cur = t & 1;
        const char* sa0 = smem + cur * 65536;
        const char* sa1 = sa0 + 16384;
        const char* sb0 = sa0 + 32768;
        const char* sb1 = sb0 + 16384;
        const bool p1 = (t + 1 < NKT), p2 = (t + 2 < NKT);
        bf16x8 b0[4], b1[4], af[4];

        // ---- s0: MFMA(kh0, m0-3); stage A-kh1(t+1) ----
#pragma unroll
        for (int n = 0; n < 4; ++n) b0[n] = *(const bf16x8*)(sb0 + wn * 4096 + n * 1024 + lb);
#pragma unroll
        for (int m = 0; m < 4; ++m) af[m] = *(const bf16x8*)(sa0 + wm * 8192 + m * 1024 + lb);
        if (p1) { STG_A(cur ^ 1, 1, t + 1); STG_W(cur ^ 1, 1, t + 1); }
        VMW(t, 0);
        __builtin_amdgcn_s_barrier();
        __builtin_amdgcn_s_setprio(1);
#pragma unroll
        for (int m = 0; m < 4; ++m)
#pragma unroll
            for (int n = 0; n < 4; ++n)
                acc[m][n] = MFMA16(af[m], b0[n], acc[m][n]);
        __builtin_amdgcn_s_setprio(0);

        // ---- s1: MFMA(kh0, m4-7) + warmup kh0; stage B-kh1(t+1) ----
#pragma unroll
        for (int m = 0; m < 4; ++m) af[m] = *(const bf16x8*)(sa0 + wm * 8192 + (m + 4) * 1024 + lb);
        if (p1) STG_B(cur ^ 1, 1, t + 1);
        VMW(t, 1);
        __builtin_amdgcn_s_barrier();
        __builtin_amdgcn_s_setprio(1);
#pragma unroll
        for (int m = 0; m < 4; ++m)
#pragma unroll
            for (int n = 0; n < 4; ++n)
                acc[m + 4][n] = MFMA16(af[m], b0[n], acc[m + 4][n]);
        __builtin_amdgcn_s_setprio(0);
        if (do_w) {
            bf16x8 awf = *(const bf16x8*)((const char*)&wabuf[cur][0][0] + lb);
#pragma unroll
            for (int n = 0; n < 4; ++n) acc_w[n] = MFMA16(awf, b0[n], acc_w[n]);
        }

        // ---- s2: MFMA(kh1, m0-3); stage A-kh0(t+2) ----
#pragma unroll
        for (int n = 0; n < 4; ++n) b1[n] = *(const bf16x8*)(sb1 + wn * 4096 + n * 1024 + lb);
#pragma unroll
        for (int m = 0; m < 4; ++m) af[m] = *(const bf16x8*)(sa1 + wm * 8192 + m * 1024 + lb);
        if (p2) { STG_A(cur, 0, t + 2); STG_W(cur, 0, t + 2); }
        VMW(t, 2);
        __builtin_amdgcn_s_barrier();
        __builtin_amdgcn_s_setprio(1);
#pragma unroll
        for (int m = 0; m < 4; ++m)
#pragma unroll
            for (int n = 0; n < 4; ++n)
                acc[m][n] = MFMA16(af[m], b1[n], acc[m][n]);
        __builtin_amdgcn_s_setprio(0);

        // ---- s3: MFMA(kh1, m4-7) + warmup kh1; stage B-kh0(t+2) ----
#pragma unroll
        for (int m = 0; m < 4; ++m) af[m] = *(const bf16x8*)(sa1 + wm * 8192 + (m + 4) * 1024 + lb);
        if (p2) STG_B(cur, 0, t + 2);
        VMW(t, 3);
        __builtin_amdgcn_s_barrier();
        __builtin_amdgcn_s_setprio(1);
#pragma unroll
        for (int m = 0; m < 4; ++m)
#pragma unroll
            for (int n = 0; n < 4; ++n)
                acc[m + 4][n] = MFMA16(af[m], b1[n], acc[m + 4][n]);
        __builtin_amdgcn_s_setprio(0);
        if (do_w) {
            bf16x8 awf = *(const bf16x8*)((const char*)&wabuf[cur][1][0] + lb);
#pragma unroll
            for (int n = 0; n < 4; ++n) acc_w[n] = MFMA16(awf, b1[n], acc_w[n]);
        }
    }
#undef STG_A
#undef STG_B
#undef STG_W

    // ---- epilogue: Bu tile -> LDS (bf16), warmup -> wstrip ----
    const int fr = lane & 15;
    const int fq = lane >> 4;
    ushort_t* cl = (ushort_t*)smem;              // [256][256] bf16 = 128 KB
#pragma unroll
    for (int m = 0; m < 8; ++m)
#pragma unroll
        for (int n = 0; n < 4; ++n) {
            const int col = wn * 64 + n * 16 + fr;
#pragma unroll
            for (int r = 0; r < 4; ++r)
                cl[(wm * 128 + m * 16 + fq * 4 + r) * 256 + col] = f2b(acc[m][n][r]);
        }
    if (do_w) {
#pragma unroll
        for (int n = 0; n < 4; ++n) {
            const int col = wn * 64 + n * 16 + fr;
#pragma unroll
            for (int r = 0; r < 4; ++r)
                wstrip[(fq * 4 + r) * 256 + col] = f2b(acc_w[n][r]);
        }
    }
    __syncthreads();

    // ---- scan: wave w owns rows [32w, 32w+32), lane owns 4 cols ----
    const int c0 = lane * 4;
    const float4 nu4 = *(const float4*)&nu_log[col0 + c0];
    float cr0 = 0.f, cr1 = 0.f, cr2 = 0.f, cr3 = 0.f;
#define SCAN_STEP(pu)                                                        \
    {   uint2 _v = (pu);                                                     \
        cr0 = fmaf(nu4.x, cr0, b2f((ushort_t)(_v.x & 0xffff)));              \
        cr1 = fmaf(nu4.y, cr1, b2f((ushort_t)(_v.x >> 16)));                 \
        cr2 = fmaf(nu4.z, cr2, b2f((ushort_t)(_v.y & 0xffff)));              \
        cr3 = fmaf(nu4.w, cr3, b2f((ushort_t)(_v.y >> 16))); }
    if (w == 0) {
        if (row0) {
#pragma unroll
            for (int t = 0; t < 16; ++t)
                SCAN_STEP(*(const uint2*)&wstrip[t * 256 + c0]);
        }
    } else {
#pragma unroll
        for (int t = 0; t < 16; ++t)
            SCAN_STEP(*(const uint2*)&cl[(w * 32 - 16 + t) * 256 + c0]);
    }
#pragma unroll
    for (int t = 0; t < 32; ++t) {
        SCAN_STEP(*(const uint2*)&cl[(w * 32 + t) * 256 + c0]);
        ushort4 o;
        o.x = f2b(cr0); o.y = f2b(cr1); o.z = f2b(cr2); o.w = f2b(cr3);
        *(ushort4*)&Hb[(size_t)(row0 + w * 32 + t) * N + col0 + c0] = o;
    }
#undef SCAN_STEP
}

// ---------------------------------------------------------------------------
// GEMM2: out = Hb*Cb^T + Dp.*Xb, same T3+T4 pipeline, f32 epilogue via LDS
// ---------------------------------------------------------------------------
__global__ __launch_bounds__(512, 2) void gemm2ph(const ushort_t* __restrict__ A,
                                                  const ushort_t* __restrict__ W,
                                                  float* __restrict__ Cout,
                                                  int M, int N, int K,
                                                  const ushort_t* __restrict__ Xres,
                                                  const float* __restrict__ Dp) {
    extern __shared__ char smem[];

    const int tid  = threadIdx.x;
    const int lane = tid & 63;
    const int w    = tid >> 6;
    const int wm   = w >> 2;
    const int wn   = w & 3;

    const int nwg = gridDim.x;
    const int cpx = nwg >> 3;
    const int bid = (blockIdx.x & 7) * cpx + (blockIdx.x >> 3);
    const int nbn = N >> 8;
    const int row0 = (bid / nbn) << 8;
    const int col0 = (bid % nbn) << 8;
    const int NKT = K >> 6;

    const int g8e = (((tid & 3) ^ ((tid >> 3) & 3)) << 3);
    const ushort_t* asrc0 = A + (size_t)(row0 +       (tid >> 2)) * K + g8e;
    const ushort_t* asrc1 = A + (size_t)(row0 + 128 + (tid >> 2)) * K + g8e;
    const ushort_t* bsrc0 = W + (size_t)(col0 +       (tid >> 2)) * K + g8e;
    const ushort_t* bsrc1 = W + (size_t)(col0 + 128 + (tid >> 2)) * K + g8e;

#define STG_A(buf, kh, kt) do {                                               \
    char* _d = smem + (buf) * 65536 + (kh) * 16384 + tid * 16;                \
    const size_t _o = (size_t)(kt) * 64 + (kh) * 32;                          \
    GLDS16(asrc0 + _o, _d);                                                   \
    GLDS16(asrc1 + _o, _d + 8192); } while (0)
#define STG_B(buf, kh, kt) do {                                               \
    char* _d = smem + (buf) * 65536 + 32768 + (kh) * 16384 + tid * 16;        \
    const size_t _o = (size_t)(kt) * 64 + (kh) * 32;                          \
    GLDS16(bsrc0 + _o, _d);                                                   \
    GLDS16(bsrc1 + _o, _d + 8192); } while (0)

    const int lb = (lane & 15) * 64 + ((((lane >> 4) ^ ((lane >> 1) & 3))) << 4);

    f32x4 acc[8][4] = {};

    STG_A(0, 0, 0); STG_B(0, 0, 0);
    STG_A(0, 1, 0); STG_B(0, 1, 0);
    STG_A(1, 0, 1); STG_B(1, 0, 1);
    asm volatile("s_waitcnt vmcnt(0)" ::: "memory");
    __builtin_amdgcn_s_barrier();

    for (int t = 0; t < NKT; ++t) {
        const int cur = t & 1;
        const char* sa0 = smem + cur * 65536;
        const char* sa1 = sa0 + 16384;
        const char* sb0 = sa0 + 32768;
        const char* sb1 = sb0 + 16384;
        const bool p1 = (t + 1 < NKT), p2 = (t + 2 < NKT);
        bf16x8 b0[4], b1[4], af[4];

        // s0
#pragma unroll
        for (int n = 0; n < 4; ++n) b0[n] = *(const bf16x8*)(sb0 + wn * 4096 + n * 1024 + lb);
#pragma unroll
        for (int m = 0; m < 4; ++m) af[m] = *(const bf16x8*)(sa0 + wm * 8192 + m * 1024 + lb);
        if (p1) STG_A(cur ^ 1, 1, t + 1);
        VMW(t, 0);
        __builtin_amdgcn_s_barrier();
        __builtin_amdgcn_s_setprio(1);
#pragma unroll
        for (int m = 0; m < 4; ++m)
#pragma unroll
            for (int n = 0; n < 4; ++n)
                acc[m][n] = MFMA16(af[m], b0[n], acc[m][n]);
        __builtin_amdgcn_s_setprio(0);

        // s1
#pragma unroll
        for (int m = 0; m < 4; ++m) af[m] = *(const bf16x8*)(sa0 + wm * 8192 + (m + 4) * 1024 + lb);
        if (p1) STG_B(cur ^ 1, 1, t + 1);
        VMW(t, 1);
        __builtin_amdgcn_s_barrier();
        __builtin_amdgcn_s_setprio(1);
#pragma unroll
        for (int m = 0; m < 4; ++m)
#pragma unroll
            for (int n = 0; n < 4; ++n)
                acc[m + 4][n] = MFMA16(af[m], b0[n], acc[m + 4][n]);
        __builtin_amdgcn_s_setprio(0);

        // s2
#pragma unroll
        for (int n = 0; n < 4; ++n) b1[n] = *(const bf16x8*)(sb1 + wn * 4096 + n * 1024 + lb);
#pragma unroll
        for (int m = 0; m < 4; ++m) af[m] = *(const bf16x8*)(sa1 + wm * 8192 + m * 1024 + lb);
        if (p2) STG_A(cur, 0, t + 2);
        VMW(t, 2);
        __builtin_amdgcn_s_barrier();
        __builtin_amdgcn_s_setprio(1);
#pragma unroll
        for (int m = 0; m < 4; ++m)
#pragma unroll
            for (int n = 0; n < 4; ++n)
                acc[m][n] = MFMA16(af[m], b1[n], acc[m][n]);
        __builtin_amdgcn_s_setprio(0);

        // s3
#pragma unroll
        for (int m = 0; m < 4; ++m) af[m] = *(const bf16x8*)(sa1 + wm * 8192 + (m + 4) * 1024 + lb);
        if (p2) STG_B(cur, 0, t + 2);
        VMW(t, 3);
        __builtin_amdgcn_s_barrier();
        __builtin_amdgcn_s_setprio(1);
#pragma unroll
        for (int m = 0; m < 4; ++m)
#pragma unroll
            for (int n = 0; n < 4; ++n)
                acc[m + 4][n] = MFMA16(af[m], b1[n], acc[m + 4][n]);
        __builtin_amdgcn_s_setprio(0);
    }
#undef STG_A
#undef STG_B

    // epilogue via LDS, f32, fused Dp.*x
    const int fr = lane & 15;
    const int fq = lane >> 4;
    float* clf = (float*)smem;                 // [128][256] f32 = 128 KB
#pragma unroll
    for (int h = 0; h < 2; ++h) {
        if (h) __builtin_amdgcn_s_barrier();
        if (wm == h) {
#pragma unroll
            for (int m = 0; m < 8; ++m)
#pragma unroll
                for (int n = 0; n < 4; ++n) {
                    const int col = wn * 64 + n * 16 + fr;
#pragma unroll
                    for (int r = 0; r < 4; ++r)
                        clf[(m * 16 + fq * 4 + r) * 256 + col] = acc[m][n][r];
                }
        }
        __builtin_amdgcn_s_barrier();
#pragma unroll
        for (int i = 0; i < 16; ++i) {
            const int q  = i * 512 + tid;
            const int rr = q >> 6, cc = (q & 63) * 4;
            float4 v = *(const float4*)(clf + rr * 256 + cc);
            const size_t grow = (size_t)(row0 + h * 128 + rr);
            ushort4 xv = *(const ushort4*)(Xres + grow * N + col0 + cc);
            float4  dp = *(const float4*)(Dp + col0 + cc);
            v.x += dp.x * b2f(xv.x); v.y += dp.y * b2f(xv.y);
            v.z += dp.z * b2f(xv.z); v.w += dp.w * b2f(xv.w);
            *(float4*)(Cout + grow * N + col0 + cc) = v;
        }
    }
}

// ---------------------------------------------------------------------------
extern "C" void kernel_launch(void* const* d_in, const int* in_sizes, int n_in,
                              void* d_out, int out_size, void* d_ws, size_t ws_size,
                              hipStream_t stream) {
    const float* X  = (const float*)d_in[0];   // [T, D]
    const float* nu = (const float*)d_in[1];   // [H]
    const float* B  = (const float*)d_in[2];   // [H, D]
    const float* C  = (const float*)d_in[3];   // [D, H]
    const float* Dp = (const float*)d_in[4];   // [D]
    float* out = (float*)d_out;                // [T, D]

    const int T = 16384, H = 1024, D = 1024;

    char* ws = (char*)d_ws;
    ushort_t* Xb  = (ushort_t*)(ws);                          // 32 MB bf16 X
    ushort_t* Bb  = (ushort_t*)(ws + ((size_t)32 << 20));     //  2 MB bf16 B
    ushort_t* Cb  = (ushort_t*)(ws + ((size_t)34 << 20));     //  2 MB bf16 C
    ushort_t* Hb  = (ushort_t*)(ws + ((size_t)36 << 20));     // 32 MB bf16 hidden

    (void)hipFuncSetAttribute((const void*)&gemm1_scan,
                              hipFuncAttributeMaxDynamicSharedMemorySize, 131072);
    (void)hipFuncSetAttribute((const void*)&gemm2ph,
                              hipFuncAttributeMaxDynamicSharedMemorySize, 131072);

    // fused converts (X, B, C)
    cvt3<<<16384 + 1024 + 1024, 256, 0, stream>>>(X, Xb, B, Bb, C, Cb);

    // GEMM1 + scan: Hb[T,H](bf16) = scan(Xb[T,D] * Bb[H,D]^T)
    gemm1_scan<<<(T / 256) * (H / 256), 512, 131072, stream>>>(
        Xb, Bb, Hb, T, H, D, nu);

    // GEMM2: out[T,D](f32) = Hb[T,H] * Cb[D,H]^T + Dp.*Xb
    gemm2ph<<<(T / 256) * (D / 256), 512, 131072, stream>>>(
        Hb, Cb, out, T, D, H, Xb, Dp);
}

// Round 8
// 100.397 us; speedup vs baseline: 1.0489x; 1.0489x over previous
//
#include <hip/hip_runtime.h>
#include <hip/hip_bf16.h>
#include <stdint.h>

typedef __attribute__((ext_vector_type(8))) __bf16 bf16x8;
typedef __attribute__((ext_vector_type(4))) float  f32x4;
typedef unsigned short ushort_t;

#define MFMA16(a, b, c) __builtin_amdgcn_mfma_f32_16x16x32_bf16((a), (b), (c), 0, 0, 0)

// f32 -> bf16 (round-to-nearest-even), raw bits
__device__ __forceinline__ ushort_t f2b(float f) {
    union { float f; uint32_t u; } v; v.f = f;
    uint32_t r = v.u + 0x7FFFu + ((v.u >> 16) & 1u);
    return (ushort_t)(r >> 16);
}
__device__ __forceinline__ float b2f(ushort_t u) {
    union { uint32_t u; float f; } v; v.u = (uint32_t)u << 16;
    return v.f;
}

#define GLDS16(g, l)                                                          \
    __builtin_amdgcn_global_load_lds(                                         \
        (const __attribute__((address_space(1))) void*)(g),                   \
        (__attribute__((address_space(3))) void*)(l), 16, 0, 0)

// ---------------------------------------------------------------------------
// fused fp32 -> bf16 convert for X, B, C in one launch (x4 vectorized)
// ---------------------------------------------------------------------------
__global__ __launch_bounds__(256) void cvt3(const float* __restrict__ X, ushort_t* __restrict__ Xb,
                                            const float* __restrict__ B, ushort_t* __restrict__ Bb,
                                            const float* __restrict__ C, ushort_t* __restrict__ Cb) {
    const int b = blockIdx.x;
    const float* src; ushort_t* dst; int base;
    if (b < 16384)      { src = X; dst = Xb; base = b; }
    else if (b < 17408) { src = B; dst = Bb; base = b - 16384; }
    else                { src = C; dst = Cb; base = b - 17408; }
    const int idx = (base * 256 + threadIdx.x) * 4;
    float4 v = *(const float4*)&src[idx];
    ushort4 o;
    o.x = f2b(v.x); o.y = f2b(v.y); o.z = f2b(v.z); o.w = f2b(v.w);
    *(ushort4*)&dst[idx] = o;
}

// ---------------------------------------------------------------------------
// GEMM1 + fused scan, r5 2-phase schedule + ANTIPHASE kh: odd waves process
// kh1 first, even waves kh0 first (kh = bit-6 XOR in the LDS offset). At any
// instant ~half the waves feed the LDS pipe while half feed the MFMA pipe,
// instead of all 8 bursting the same pipe in lockstep.
// ---------------------------------------------------------------------------
__global__ __launch_bounds__(512, 2) void gemm1_scan(const ushort_t* __restrict__ A,
                                                     const ushort_t* __restrict__ W,
                                                     ushort_t* __restrict__ Hb,
                                                     int M, int N, int K,
                                                     const float* __restrict__ nu_log) {
    constexpr int BK = 64;
    extern __shared__ char smem[];
    __shared__ ushort_t wstrip[16 * 256];       // warmup Bu strip (bf16)
    __shared__ char     wabuf[2][2048];         // warmup A staging, 2 bufs

    const int tid  = threadIdx.x;
    const int lane = tid & 63;
    const int w    = tid >> 6;   // wave 0..7
    const int wm   = w >> 2;     // 0..1
    const int wn   = w & 3;      // 0..3

    const int nwg = gridDim.x;
    const int cpx = nwg >> 3;
    const int bid = (blockIdx.x & 7) * cpx + (blockIdx.x >> 3);
    const int nbn = N >> 8;
    const int row0 = (bid / nbn) << 8;
    const int col0 = (bid % nbn) << 8;
    const int NKT = K / BK;

    // ---- staging geometry: linear LDS dest, pre-swizzled source ----
    const int st_r = tid >> 3;
    const int g8   = ((tid & 7) ^ (st_r & 7)) * 8;
    const ushort_t* asrc[4];
    const ushort_t* bsrc[4];
#pragma unroll
    for (int j = 0; j < 4; ++j) {
        asrc[j] = A + (size_t)(row0 + j * 64 + st_r) * K + g8;
        bsrc[j] = W + (size_t)(col0 + j * 64 + st_r) * K + g8;
    }
    const int st_lds = tid * 16;

    // warmup strip staging: threads 0..127 (waves 0,1), rows row0-16..row0-1
    const int st_rw = tid >> 3;
    const int g8w   = ((tid & 7) ^ (st_rw & 7)) * 8;
    const ushort_t* wsrc = A + (size_t)(row0 - 16 + st_rw) * K + g8w;

#define STAGE(buf, kt) {                                                      \
    char* _la = smem + (buf) * 65536;                                         \
    char* _lb = _la + 32768;                                                  \
    const int _ko = (kt) * BK;                                                \
    _Pragma("unroll")                                                         \
    for (int j = 0; j < 4; ++j) {                                             \
        GLDS16(asrc[j] + _ko, _la + j * 8192 + st_lds);                       \
        GLDS16(bsrc[j] + _ko, _lb + j * 8192 + st_lds);                       \
    }                                                                         \
    if (row0 && w < 2) GLDS16(wsrc + _ko, &wabuf[buf][0] + tid * 16); }

    // ---- fragment read base offsets (kh = XOR of bit 6) ----
    const int l15 = lane & 15;
    const int l7  = lane & 7;
    const int ch  = lane >> 4;
    const int aoff0 = (wm * 128 + l15) * 128 + ((ch ^ l7) << 4);
    const int boff0 = (wn * 64  + l15) * 128 + ((ch ^ l7) << 4);
    const int woff0 = l15 * 128 + ((ch ^ l7) << 4);
    const int kxw   = (w & 1) << 6;             // wave-parity antiphase

    f32x4 acc[8][4] = {};
    f32x4 acc_w[4] = {};
    const bool do_w = (wm == 0) && row0;

    STAGE(0, 0);
    asm volatile("s_waitcnt vmcnt(0)" ::: "memory");
    __builtin_amdgcn_s_barrier();

    int cur = 0;
    for (int kt = 0; kt < NKT; ++kt) {
        if (kt + 1 < NKT) STAGE(cur ^ 1, kt + 1);
        const char* sa = smem + cur * 65536;
        const char* sb = sa + 32768;
#pragma unroll
        for (int s = 0; s < 2; ++s) {
            const int kx = (s << 6) ^ kxw;      // this wave's kh for step s
            bf16x8 bfr[4], afr[8];
#pragma unroll
            for (int n = 0; n < 4; ++n)
                bfr[n] = *(const bf16x8*)(sb + (boff0 ^ kx) + n * 2048);
#pragma unroll
            for (int m = 0; m < 8; ++m)
                afr[m] = *(const bf16x8*)(sa + (aoff0 ^ kx) + m * 2048);
            __builtin_amdgcn_s_setprio(1);
#pragma unroll
            for (int m = 0; m < 8; ++m)
#pragma unroll
                for (int n = 0; n < 4; ++n)
                    acc[m][n] = MFMA16(afr[m], bfr[n], acc[m][n]);
            __builtin_amdgcn_s_setprio(0);
            if (do_w) {
                bf16x8 awf = *(const bf16x8*)(&wabuf[cur][0] + (woff0 ^ kx));
#pragma unroll
                for (int n = 0; n < 4; ++n) acc_w[n] = MFMA16(awf, bfr[n], acc_w[n]);
            }
        }
        asm volatile("s_waitcnt vmcnt(0)" ::: "memory");
        __builtin_amdgcn_s_barrier();
        cur ^= 1;
    }
#undef STAGE

    // ---- epilogue: Bu tile -> LDS, warmup -> wstrip ----
    const int fr = l15;
    const int fq = lane >> 4;
    ushort_t* cl = (ushort_t*)smem;             // [256][256] bf16 = 128 KB
#pragma unroll
    for (int m = 0; m < 8; ++m)
#pragma unroll
        for (int n = 0; n < 4; ++n) {
            const int col = wn * 64 + n * 16 + fr;
#pragma unroll
            for (int r = 0; r < 4; ++r)
                cl[(wm * 128 + m * 16 + fq * 4 + r) * 256 + col] = f2b(acc[m][n][r]);
        }
    if (do_w) {
#pragma unroll
        for (int n = 0; n < 4; ++n) {
            const int col = wn * 64 + n * 16 + fr;
#pragma unroll
            for (int r = 0; r < 4; ++r)
                wstrip[(fq * 4 + r) * 256 + col] = f2b(acc_w[n][r]);
        }
    }
    __syncthreads();

    // ---- scan: wave w owns rows [32w, 32w+32), lane owns 4 cols ----
    const int c0 = lane * 4;
    const float4 nu4 = *(const float4*)&nu_log[col0 + c0];
    float cr0 = 0.f, cr1 = 0.f, cr2 = 0.f, cr3 = 0.f;
#define SCAN_STEP(pu)                                                        \
    {   uint2 _v = (pu);                                                     \
        cr0 = fmaf(nu4.x, cr0, b2f((ushort_t)(_v.x & 0xffff)));              \
        cr1 = fmaf(nu4.y, cr1, b2f((ushort_t)(_v.x >> 16)));                 \
        cr2 = fmaf(nu4.z, cr2, b2f((ushort_t)(_v.y & 0xffff)));              \
        cr3 = fmaf(nu4.w, cr3, b2f((ushort_t)(_v.y >> 16))); }
    if (w == 0) {
        if (row0) {
#pragma unroll
            for (int t = 0; t < 16; ++t)
                SCAN_STEP(*(const uint2*)&wstrip[t * 256 + c0]);
        }
    } else {
#pragma unroll
        for (int t = 0; t < 16; ++t)
            SCAN_STEP(*(const uint2*)&cl[(w * 32 - 16 + t) * 256 + c0]);
    }
#pragma unroll
    for (int t = 0; t < 32; ++t) {
        SCAN_STEP(*(const uint2*)&cl[(w * 32 + t) * 256 + c0]);
        ushort4 o;
        o.x = f2b(cr0); o.y = f2b(cr1); o.z = f2b(cr2); o.w = f2b(cr3);
        *(ushort4*)&Hb[(size_t)(row0 + w * 32 + t) * N + col0 + c0] = o;
    }
#undef SCAN_STEP
}

// ---------------------------------------------------------------------------
// GEMM2: out = Hb*Cb^T + Dp.*Xb, same antiphase 2-phase K-loop
// ---------------------------------------------------------------------------
__global__ __launch_bounds__(512, 2) void gemm2ph(const ushort_t* __restrict__ A,
                                                  const ushort_t* __restrict__ W,
                                                  float* __restrict__ Cout,
                                                  int M, int N, int K,
                                                  const ushort_t* __restrict__ Xres,
                                                  const float* __restrict__ Dp) {
    constexpr int BK = 64;
    extern __shared__ char smem[];

    const int tid  = threadIdx.x;
    const int lane = tid & 63;
    const int w    = tid >> 6;
    const int wm   = w >> 2;
    const int wn   = w & 3;

    const int nwg = gridDim.x;
    const int cpx = nwg >> 3;
    const int bid = (blockIdx.x & 7) * cpx + (blockIdx.x >> 3);
    const int nbn = N >> 8;
    const int row0 = (bid / nbn) << 8;
    const int col0 = (bid % nbn) << 8;
    const int NKT = K / BK;

    const int st_r = tid >> 3;
    const int g8   = ((tid & 7) ^ (st_r & 7)) * 8;
    const ushort_t* asrc[4];
    const ushort_t* bsrc[4];
#pragma unroll
    for (int j = 0; j < 4; ++j) {
        asrc[j] = A + (size_t)(row0 + j * 64 + st_r) * K + g8;
        bsrc[j] = W + (size_t)(col0 + j * 64 + st_r) * K + g8;
    }
    const int st_lds = tid * 16;

#define STAGE(buf, kt) {                                                      \
    char* _la = smem + (buf) * 65536;                                         \
    char* _lb = _la + 32768;                                                  \
    const int _ko = (kt) * BK;                                                \
    _Pragma("unroll")                                                         \
    for (int j = 0; j < 4; ++j) {                                             \
        GLDS16(asrc[j] + _ko, _la + j * 8192 + st_lds);                       \
        GLDS16(bsrc[j] + _ko, _lb + j * 8192 + st_lds);                       \
    } }

    const int l15 = lane & 15;
    const int l7  = lane & 7;
    const int ch  = lane >> 4;
    const int aoff0 = (wm * 128 + l15) * 128 + ((ch ^ l7) << 4);
    const int boff0 = (wn * 64  + l15) * 128 + ((ch ^ l7) << 4);
    const int kxw   = (w & 1) << 6;

    f32x4 acc[8][4] = {};

    STAGE(0, 0);
    asm volatile("s_waitcnt vmcnt(0)" ::: "memory");
    __builtin_amdgcn_s_barrier();

    int cur = 0;
    for (int kt = 0; kt < NKT; ++kt) {
        if (kt + 1 < NKT) STAGE(cur ^ 1, kt + 1);
        const char* sa = smem + cur * 65536;
        const char* sb = sa + 32768;
#pragma unroll
        for (int s = 0; s < 2; ++s) {
            const int kx = (s << 6) ^ kxw;
            bf16x8 bfr[4], afr[8];
#pragma unroll
            for (int n = 0; n < 4; ++n)
                bfr[n] = *(const bf16x8*)(sb + (boff0 ^ kx) + n * 2048);
#pragma unroll
            for (int m = 0; m < 8; ++m)
                afr[m] = *(const bf16x8*)(sa + (aoff0 ^ kx) + m * 2048);
            __builtin_amdgcn_s_setprio(1);
#pragma unroll
            for (int m = 0; m < 8; ++m)
#pragma unroll
                for (int n = 0; n < 4; ++n)
                    acc[m][n] = MFMA16(afr[m], bfr[n], acc[m][n]);
            __builtin_amdgcn_s_setprio(0);
        }
        asm volatile("s_waitcnt vmcnt(0)" ::: "memory");
        __builtin_amdgcn_s_barrier();
        cur ^= 1;
    }
#undef STAGE

    // epilogue via LDS, f32, fused Dp.*x
    const int fr = l15;
    const int fq = lane >> 4;
    float* clf = (float*)smem;                 // [128][256] f32 = 128 KB
#pragma unroll
    for (int h = 0; h < 2; ++h) {
        if (h) __builtin_amdgcn_s_barrier();
        if (wm == h) {
#pragma unroll
            for (int m = 0; m < 8; ++m)
#pragma unroll
                for (int n = 0; n < 4; ++n) {
                    const int col = wn * 64 + n * 16 + fr;
#pragma unroll
                    for (int r = 0; r < 4; ++r)
                        clf[(m * 16 + fq * 4 + r) * 256 + col] = acc[m][n][r];
                }
        }
        __builtin_amdgcn_s_barrier();
#pragma unroll
        for (int i = 0; i < 16; ++i) {
            const int q  = i * 512 + tid;
            const int rr = q >> 6, cc = (q & 63) * 4;
            float4 v = *(const float4*)(clf + rr * 256 + cc);
            const size_t grow = (size_t)(row0 + h * 128 + rr);
            ushort4 xv = *(const ushort4*)(Xres + grow * N + col0 + cc);
            float4  dp = *(const float4*)(Dp + col0 + cc);
            v.x += dp.x * b2f(xv.x); v.y += dp.y * b2f(xv.y);
            v.z += dp.z * b2f(xv.z); v.w += dp.w * b2f(xv.w);
            *(float4*)(Cout + grow * N + col0 + cc) = v;
        }
    }
}

// ---------------------------------------------------------------------------
extern "C" void kernel_launch(void* const* d_in, const int* in_sizes, int n_in,
                              void* d_out, int out_size, void* d_ws, size_t ws_size,
                              hipStream_t stream) {
    const float* X  = (const float*)d_in[0];   // [T, D]
    const float* nu = (const float*)d_in[1];   // [H]
    const float* B  = (const float*)d_in[2];   // [H, D]
    const float* C  = (const float*)d_in[3];   // [D, H]
    const float* Dp = (const float*)d_in[4];   // [D]
    float* out = (float*)d_out;                // [T, D]

    const int T = 16384, H = 1024, D = 1024;

    char* ws = (char*)d_ws;
    ushort_t* Xb  = (ushort_t*)(ws);                          // 32 MB bf16 X
    ushort_t* Bb  = (ushort_t*)(ws + ((size_t)32 << 20));     //  2 MB bf16 B
    ushort_t* Cb  = (ushort_t*)(ws + ((size_t)34 << 20));     //  2 MB bf16 C
    ushort_t* Hb  = (ushort_t*)(ws + ((size_t)36 << 20));     // 32 MB bf16 hidden

    (void)hipFuncSetAttribute((const void*)&gemm1_scan,
                              hipFuncAttributeMaxDynamicSharedMemorySize, 131072);
    (void)hipFuncSetAttribute((const void*)&gemm2ph,
                              hipFuncAttributeMaxDynamicSharedMemorySize, 131072);

    // fused converts (X, B, C)
    cvt3<<<16384 + 1024 + 1024, 256, 0, stream>>>(X, Xb, B, Bb, C, Cb);

    // GEMM1 + scan: Hb[T,H](bf16) = scan(Xb[T,D] * Bb[H,D]^T)
    gemm1_scan<<<(T / 256) * (H / 256), 512, 131072, stream>>>(
        Xb, Bb, Hb, T, H, D, nu);

    // GEMM2: out[T,D](f32) = Hb[T,H] * Cb[D,H]^T + Dp.*Xb
    gemm2ph<<<(T / 256) * (D / 256), 512, 131072, stream>>>(
        Hb, Cb, out, T, D, H, Xb, Dp);
}